// Round 3
// baseline (2899.202 us; speedup 1.0000x reference)
//
#include <hip/hip_runtime.h>
#include <math.h>

#define Hdim 2048
#define Ldim 256
#define NBLK 256
#define TPB  1024
#define JPB  8      // h-elements per block (Hdim / NBLK)
#define NREP 8      // replicas of the published h (consumers shard by b&7)

typedef unsigned long long u64;

// workspace: packed replicated h buffer: [parity][replica][2048] u32 words.
// word = (f32 bits & 0xFFFFFF00) | step_tag8  — tag rides in the mantissa
// low byte (<=3e-5 relative perturbation). Detect = equality with t.
// Race-freedom: a block publishes tag t+1 only after it polled tag t on all
// 2048 words, which requires EVERY block to have published tag t, which
// requires every block to have fully consumed tag t-1 — so no consumer can
// still be waiting on a tag-(t-1) word when it is overwritten.
#define WS_HP 0

__device__ __forceinline__ float fast_sigmoid(float x) {
    return __builtin_amdgcn_rcpf(1.0f + __expf(-x));
}
__device__ __forceinline__ float fast_tanh(float x) {
    // 1 - 2/(1+e^{2x}); saturates correctly at +/-inf
    return 1.0f - 2.0f * __builtin_amdgcn_rcpf(1.0f + __expf(2.0f * x));
}

// ---------------- single fused persistent kernel ----------------------------
// 256 blocks x 1024 threads, 1 block/CU. Block b owns h[j], j = b*8..b*8+7.
// v2'': ONE barrier per step. Pair g (waves 2g,2g+1) owns j=b*8+g: dots
// (incl. fused W_out dot) reduce in-wave; odd wave hands partials to even
// wave via tagged LDS flag; even lane0 computes gates and publishes its j
// immediately — no block-wide B2, no wave0 funnel. setprio(1) on the even
// waves' tail (T5: step tail has real wave role-diversity).
__global__ __launch_bounds__(TPB, 4) void gru_all(
    const float* __restrict__ Whh,  const float* __restrict__ bhh,
    const float* __restrict__ Wout, const float* __restrict__ bout,
    const float* __restrict__ tps,  const float* __restrict__ pkdata,
    const int*   __restrict__ tf,   const float* __restrict__ smiles,
    const float* __restrict__ Wp,   const float* __restrict__ bpre,
    const float* __restrict__ Wih,  const float* __restrict__ bih,
    const float* __restrict__ dose, const float* __restrict__ route,
    const float* __restrict__ emb,  const int* __restrict__ pat,
    float* __restrict__ ws, float* __restrict__ out)
{
    const int b    = blockIdx.x;
    const int tid  = threadIdx.x;
    const int kk   = tid & 127;     // column group within pair
    const int g    = tid >> 7;      // pair id == owned j offset
    const int wv   = tid >> 6;      // wave id 0..15
    const int lane = tid & 63;
    const int j    = b*JPB + g;
    const int rep  = b & 7;         // this block's poll replica
    const int i0   = tid * 2;

    __shared__ float su[Hdim];          // u vector (prep only)
    __shared__ float sh_h[2][Hdim];     // parity-buffered staged h
    __shared__ float sWout[Hdim];       // W_out resident in LDS
    __shared__ float sred_A[24], sred_T[24], sred_C[24]; // APK/ATP/CVT rows
    __shared__ float s_tp[Ldim];
    __shared__ float s_pkd[Ldim];
    __shared__ int   s_tf[Ldim];
    __shared__ float spair[JPB][4];     // odd-wave partials: r,z,n,w
    __shared__ unsigned sflag[JPB];     // pair handoff flags (= step t)
    __shared__ float sfin[16];          // final-output reduce buffer

    unsigned* hq = (unsigned*)(ws + WS_HP);

    // small per-step scalars
    for (int i = tid; i < Ldim; i += TPB) {
        s_tp[i]  = tps[i];
        s_pkd[i] = pkdata[i];
        s_tf[i]  = tf[i];
    }
    if (tid < JPB) sflag[tid] = 0xFFFFFFFFu;   // never matches t in [0,255)

    // ---- prep A: u[i] = Wp[i,2:7].consts + b_pre[i] into LDS; W_out->LDS --
    {
        float d = dose[0], rt = route[0];
        int p = pat[0];
        float e0 = emb[p*3+0], e1 = emb[p*3+1], e2 = emb[p*3+2];
        for (int i = tid; i < Hdim; i += TPB) {
            const float* wr = Wp + i*7;
            su[i] = d*wr[2] + e0*wr[3] + e1*wr[4] + e2*wr[5] + rt*wr[6] + bpre[i];
            sWout[i] = Wout[i];
        }
    }

    // W_hh rows -> registers (48 VGPRs), coalesced float4 loads
    float4 w[3][4];
    #pragma unroll
    for (int r = 0; r < 3; ++r) {
        const float* base = Whh + (size_t)(j + r*Hdim) * Hdim;
        #pragma unroll
        for (int c = 0; c < 4; ++c)
            w[r][c] = *(const float4*)(base + c*512 + kk*4);
    }

    const float bo = bout[0];

    __syncthreads();   // su, sWout, sflag ready

    // ---- prep B: fold this block's 24 W_ih rows ----
    #pragma unroll
    for (int pass = 0; pass < 2; ++pass) {
        int ri = wv + pass*16;
        if (ri < 24) {
            int grow = (ri >> 3)*Hdim + b*JPB + (ri & 7);
            const float* wr = Wih + (size_t)grow * Hdim;
            float s0 = 0.f, s1 = 0.f, s2 = 0.f;
            #pragma unroll
            for (int c = 0; c < 8; ++c) {
                int col = c*256 + lane*4;
                float4 wv4 = *(const float4*)(wr + col);
                float4 uv4 = *(const float4*)(su + col);
                s0 += wv4.x*Wp[(col+0)*7+0] + wv4.y*Wp[(col+1)*7+0]
                    + wv4.z*Wp[(col+2)*7+0] + wv4.w*Wp[(col+3)*7+0];
                s1 += wv4.x*Wp[(col+0)*7+1] + wv4.y*Wp[(col+1)*7+1]
                    + wv4.z*Wp[(col+2)*7+1] + wv4.w*Wp[(col+3)*7+1];
                s2 += wv4.x*uv4.x + wv4.y*uv4.y + wv4.z*uv4.z + wv4.w*uv4.w;
            }
            #pragma unroll
            for (int off = 32; off >= 1; off >>= 1) {
                s0 += __shfl_down(s0, off, 64);
                s1 += __shfl_down(s1, off, 64);
                s2 += __shfl_down(s2, off, 64);
            }
            if (lane == 0) {
                sred_A[ri] = s0;
                sred_T[ri] = s1;
                sred_C[ri] = s2 + bih[grow];
            }
        }
    }
    __syncthreads();   // sred_A/T/C ready

    // ---- pair-leader constants (even-wave lane0 of each pair) ----
    float apk_r=0, apk_z=0, apk_n=0, atp_r=0, atp_z=0, atp_n=0,
          cvt_r=0, cvt_z=0, cvt_n=0, br=0, bz=0, bn=0, hprev=0;
    const bool evenw = ((wv & 1) == 0);
    if (evenw && lane == 0) {
        int gg = wv >> 1;
        int jj = b*JPB + gg;
        apk_r = sred_A[gg]; apk_z = sred_A[8+gg]; apk_n = sred_A[16+gg];
        atp_r = sred_T[gg]; atp_z = sred_T[8+gg]; atp_n = sred_T[16+gg];
        cvt_r = sred_C[gg]; cvt_z = sred_C[8+gg]; cvt_n = sred_C[16+gg];
        br = bhh[jj]; bz = bhh[jj + Hdim]; bn = bhh[jj + 2*Hdim];
        hprev = smiles[jj];
    }

    // ---- h0 publish (tag 0): each even wave stores its pair's j to 8 reps --
    if (evenw) {
        int gg = wv >> 1;
        if (lane < NREP) {
            float hinit = smiles[b*JPB + gg];
            unsigned w0 = __float_as_uint(hinit) & 0xFFFFFF00u;   // tag 0
            __hip_atomic_store(hq + (size_t)lane*Hdim + b*JPB + gg, w0,
                               __ATOMIC_RELAXED, __HIP_MEMORY_SCOPE_AGENT);
        }
    }
    if (b == 0 && tid == 0) out[0] = pkdata[0];

    // ================== main recurrence loop (ONE barrier/step) =============
    for (int t = 0; t < Ldim - 1; ++t) {
        const int pr_ = t & 1;
        const unsigned* hin = hq + (size_t)(pr_*NREP + rep)*Hdim;
        const unsigned tt = (unsigned)t & 0xFFu;

        // ---- poll: ONE 8B load = detect AND payload (own replica only) ----
        u64 q;
        for (;;) {
            q = __hip_atomic_load((const u64*)(hin + i0),
                                  __ATOMIC_RELAXED, __HIP_MEMORY_SCOPE_AGENT);
            if (((unsigned)q & 0xFFu) == tt &&
                ((unsigned)(q >> 32) & 0xFFu) == tt) break;
        }
        float h0 = __uint_as_float((unsigned)q         & 0xFFFFFF00u);
        float h1 = __uint_as_float((unsigned)(q >> 32) & 0xFFFFFF00u);
        sh_h[pr_][i0]     = h0;
        sh_h[pr_][i0 + 1] = h1;
        __syncthreads();                       // B1: h staged (only barrier)

        // ---- dots: r,z,n + fused W_out dot, 4 accumulators, from LDS ----
        float prd = 0.f, pzd = 0.f, pnd = 0.f, pwd = 0.f;
        #pragma unroll
        for (int c = 0; c < 4; ++c) {
            float4 hv4 = *(const float4*)(&sh_h[pr_][c*512 + kk*4]);
            float4 ov4 = *(const float4*)(&sWout[c*512 + kk*4]);
            prd += w[0][c].x*hv4.x + w[0][c].y*hv4.y + w[0][c].z*hv4.z + w[0][c].w*hv4.w;
            pzd += w[1][c].x*hv4.x + w[1][c].y*hv4.y + w[1][c].z*hv4.z + w[1][c].w*hv4.w;
            pnd += w[2][c].x*hv4.x + w[2][c].y*hv4.y + w[2][c].z*hv4.z + w[2][c].w*hv4.w;
            pwd += ov4.x*hv4.x + ov4.y*hv4.y + ov4.z*hv4.z + ov4.w*hv4.w;
        }
        #pragma unroll
        for (int off = 32; off >= 1; off >>= 1) {
            prd += __shfl_down(prd, off, 64);
            pzd += __shfl_down(pzd, off, 64);
            pnd += __shfl_down(pnd, off, 64);
            pwd += __shfl_down(pwd, off, 64);
        }

        // even waves are the critical path from here to publish
        if (evenw) __builtin_amdgcn_s_setprio(1);

        float hvnew = 0.f, predv = 0.f;
        if (lane == 0) {
            int gg = wv >> 1;
            if (!evenw) {
                // odd wave: hand partials to pair leader via tagged flag
                spair[gg][0] = prd; spair[gg][1] = pzd;
                spair[gg][2] = pnd; spair[gg][3] = pwd;
                __hip_atomic_store(&sflag[gg], (unsigned)t,
                                   __ATOMIC_RELEASE, __HIP_MEMORY_SCOPE_WORKGROUP);
            } else {
                // even lane0: combine, gates, new h for own j
                while (__hip_atomic_load(&sflag[gg], __ATOMIC_ACQUIRE,
                                         __HIP_MEMORY_SCOPE_WORKGROUP) != (unsigned)t) {}
                volatile float* sp = &spair[gg][0];
                float dotr = prd + sp[0];
                float dotz = pzd + sp[1];
                float dotn = pnd + sp[2];
                predv      = pwd + sp[3] + bo;          // pred_{t-1} = W_out.h_t
                float pk = (t == 0) ? s_pkd[0]
                                    : ((s_tf[t] == 1) ? predv : s_pkd[t]);
                float tp  = s_tp[t];
                float gr  = apk_r*pk + atp_r*tp + cvt_r + dotr + br;
                float gz  = apk_z*pk + atp_z*tp + cvt_z + dotz + bz;
                float gin = apk_n*pk + atp_n*tp + cvt_n;
                float r = fast_sigmoid(gr);
                float z = fast_sigmoid(gz);
                float n = fast_tanh(gin + r*(dotn + bn));
                hvnew = (1.0f - z)*n + z*hprev;
                hprev = hvnew;
            }
        }

        // ---- per-pair publish: even wave lanes 0-7 store to 8 replicas ----
        if (evenw) {
            float hv = __shfl(hvnew, 0, 64);
            if (lane < NREP) {
                unsigned wpk = (__float_as_uint(hv) & 0xFFFFFF00u)
                             | ((unsigned)(t + 1) & 0xFFu);
                __hip_atomic_store(hq + (size_t)((pr_^1)*NREP + lane)*Hdim
                                       + b*JPB + (wv >> 1), wpk,
                                   __ATOMIC_RELAXED, __HIP_MEMORY_SCOPE_AGENT);
            }
            __builtin_amdgcn_s_setprio(0);
            if (b == 0 && wv == 0 && lane == 0 && t > 0) out[t] = predv;
        }
    }

    // ---- final: block 0 polls h_255 (parity 1, replica 0), writes out[255] -
    if (b == 0) {
        const unsigned* hin = hq + (size_t)(1*NREP + 0)*Hdim;
        const unsigned tt = (unsigned)(Ldim - 1) & 0xFFu;
        u64 q;
        for (;;) {
            q = __hip_atomic_load((const u64*)(hin + i0),
                                  __ATOMIC_RELAXED, __HIP_MEMORY_SCOPE_AGENT);
            if (((unsigned)q & 0xFFu) == tt &&
                ((unsigned)(q >> 32) & 0xFFu) == tt) break;
        }
        float h0 = __uint_as_float((unsigned)q         & 0xFFFFFF00u);
        float h1 = __uint_as_float((unsigned)(q >> 32) & 0xFFFFFF00u);
        float wpart = sWout[i0]*h0 + sWout[i0 + 1]*h1;
        #pragma unroll
        for (int off = 32; off >= 1; off >>= 1) wpart += __shfl_down(wpart, off, 64);
        if (lane == 0) sfin[wv] = wpart;
        __syncthreads();
        if (wv == 0) {
            float s = (lane < 16) ? sfin[lane] : 0.f;
            s += __shfl_down(s, 8, 64);
            s += __shfl_down(s, 4, 64);
            s += __shfl_down(s, 2, 64);
            s += __shfl_down(s, 1, 64);
            if (lane == 0) out[Ldim - 1] = s + bo;
        }
    }
}

extern "C" void kernel_launch(void* const* d_in, const int* in_sizes, int n_in,
                              void* d_out, int out_size, void* d_ws, size_t ws_size,
                              hipStream_t stream)
{
    const float* tps    = (const float*)d_in[0];   // timepoints (256,1)
    const float* pkdata = (const float*)d_in[1];   // pk_data (256,1)
    // d_in[2] = input_len (unused, static 256)
    const int*   pat    = (const int*)  d_in[3];   // emb_patient
    const float* route  = (const float*)d_in[4];   // drug_route (1,)
    const float* dose   = (const float*)d_in[5];   // dose (1,)
    const float* smiles = (const float*)d_in[6];   // (1, 2048)
    const int*   tfm    = (const int*)  d_in[7];   // tf_mask (256,)
    const float* emb    = (const float*)d_in[8];   // emb_table (8,3)
    const float* Wp     = (const float*)d_in[9];   // W_pre (2048,7)
    const float* bpre   = (const float*)d_in[10];  // b_pre (2048,)
    const float* Wih    = (const float*)d_in[11];  // W_ih (6144,2048)
    const float* Whh    = (const float*)d_in[12];  // W_hh (6144,2048)
    const float* bih    = (const float*)d_in[13];  // b_ih (6144,)
    const float* bhh    = (const float*)d_in[14];  // b_hh (6144,)
    const float* Wout   = (const float*)d_in[15];  // W_out (1,2048)
    const float* bout   = (const float*)d_in[16];  // b_out (1,)
    float* out = (float*)d_out;
    float* ws  = (float*)d_ws;

    hipLaunchKernelGGL(gru_all, dim3(NBLK), dim3(TPB), 0, stream,
                       Whh, bhh, Wout, bout, tps, pkdata, tfm, smiles,
                       Wp, bpre, Wih, bih, dose, route, emb, pat, ws, out);
}

// Round 8
// 972.989 us; speedup vs baseline: 2.9797x; 2.9797x over previous
//
#include <hip/hip_runtime.h>
#include <math.h>

#define Hdim 2048
#define Ldim 256
#define NBLK 256
#define TPB  1024
#define JPB  8      // h-elements per block (Hdim / NBLK)
#define NREP 8      // replicas of the published h (consumers shard by b&7)

typedef unsigned long long u64;

// workspace: packed replicated h buffer: [parity][replica][2048] u32 words.
// word = (f32 bits & 0xFFFFFF00) | step_tag8  — tag rides in the mantissa
// low byte (<=3e-5 relative perturbation). Detect = equality with t.
// Race-free (2-phase: wave0 publishes only after B2, which proves all waves
// passed B1 of this step, i.e. everyone is done reading the parity being
// overwritten).
//
// r10 post-mortem note: do NOT decompose the wave0 publish into per-pair
// stores — v2'' measured 2899us (vs 1010 baseline): scattered 4B stores
// caused ~10x write amplification (WRITE_SIZE 161MB) and staggered tag
// visibility, ballooning the per-step global sync tail. The single
// wave-store covering all 8 replicas x 8 words is load-bearing.
#define WS_HP 0

__device__ __forceinline__ float fast_sigmoid(float x) {
    return __builtin_amdgcn_rcpf(1.0f + __expf(-x));
}
__device__ __forceinline__ float fast_tanh(float x) {
    // 1 - 2/(1+e^{2x}); saturates correctly at +/-inf
    return 1.0f - 2.0f * __builtin_amdgcn_rcpf(1.0f + __expf(2.0f * x));
}

// ---------------- single fused persistent kernel ----------------------------
// 256 blocks x 1024 threads, 1 block/CU. Block b owns h[j], j = b*8..b*8+7.
// Proven r9 protocol (1010us): minimum-hop tagged payload, 8x replicated;
// producer wave0 emits ONE wave-store covering all replicas; consumer block
// polls only replica b&7 with ONE 8B load = detect+payload.
// r10 deltas (tail-local only): fast sigmoid/tanh on wave0 tail + setprio(1)
// around wave0's reduce->gates->publish (no spin ever held at prio 1).
__global__ __launch_bounds__(TPB, 4) void gru_all(
    const float* __restrict__ Whh,  const float* __restrict__ bhh,
    const float* __restrict__ Wout, const float* __restrict__ bout,
    const float* __restrict__ tps,  const float* __restrict__ pkdata,
    const int*   __restrict__ tf,   const float* __restrict__ smiles,
    const float* __restrict__ Wp,   const float* __restrict__ bpre,
    const float* __restrict__ Wih,  const float* __restrict__ bih,
    const float* __restrict__ dose, const float* __restrict__ route,
    const float* __restrict__ emb,  const int* __restrict__ pat,
    float* __restrict__ ws, float* __restrict__ out)
{
    const int b    = blockIdx.x;
    const int tid  = threadIdx.x;
    const int k    = tid & 127;     // column group within j (dots)
    const int g    = tid >> 7;      // which j this thread's dot serves
    const int wv   = tid >> 6;      // wave id 0..15
    const int lane = tid & 63;
    const int j    = b*JPB + g;
    const int rep  = b & 7;         // this block's poll replica

    __shared__ float su[Hdim];      // u vector (prep only)
    __shared__ float sh_h[Hdim];
    __shared__ float sred[16][3];
    __shared__ float swp[2][16];
    __shared__ float sA[24], sT[24], sC[24];   // APK/ATP/CVT for own 24 rows
    __shared__ float s_tp[Ldim];
    __shared__ float s_pkd[Ldim];
    __shared__ int   s_tf[Ldim];

    unsigned* hq = (unsigned*)(ws + WS_HP);

    // small per-step scalars
    for (int i = tid; i < Ldim; i += TPB) {
        s_tp[i]  = tps[i];
        s_pkd[i] = pkdata[i];
        s_tf[i]  = tf[i];
    }

    // ---- prep A: u[i] = Wp[i,2:7].consts + b_pre[i] into LDS ----
    {
        float d = dose[0], rt = route[0];
        int p = pat[0];
        float e0 = emb[p*3+0], e1 = emb[p*3+1], e2 = emb[p*3+2];
        for (int i = tid; i < Hdim; i += TPB) {
            const float* wr = Wp + i*7;
            su[i] = d*wr[2] + e0*wr[3] + e1*wr[4] + e2*wr[5] + rt*wr[6] + bpre[i];
        }
    }

    // W_hh rows -> registers (48 VGPRs), coalesced float4 loads
    float4 w[3][4];
    #pragma unroll
    for (int r = 0; r < 3; ++r) {
        const float* base = Whh + (size_t)(j + r*Hdim) * Hdim;
        #pragma unroll
        for (int c = 0; c < 4; ++c)
            w[r][c] = *(const float4*)(base + c*512 + k*4);
    }

    // per-thread W_out slice
    const int i0 = tid * 2;
    const float wo0 = Wout[i0], wo1 = Wout[i0 + 1];
    const float bo = bout[0];

    __syncthreads();   // su ready

    // ---- prep B: fold this block's 24 W_ih rows ----
    #pragma unroll
    for (int pass = 0; pass < 2; ++pass) {
        int ri = wv + pass*16;
        if (ri < 24) {
            int grow = (ri >> 3)*Hdim + b*JPB + (ri & 7);
            const float* wr = Wih + (size_t)grow * Hdim;
            float s0 = 0.f, s1 = 0.f, s2 = 0.f;
            #pragma unroll
            for (int c = 0; c < 8; ++c) {
                int col = c*256 + lane*4;
                float4 wv4 = *(const float4*)(wr + col);
                float4 uv4 = *(const float4*)(su + col);
                s0 += wv4.x*Wp[(col+0)*7+0] + wv4.y*Wp[(col+1)*7+0]
                    + wv4.z*Wp[(col+2)*7+0] + wv4.w*Wp[(col+3)*7+0];
                s1 += wv4.x*Wp[(col+0)*7+1] + wv4.y*Wp[(col+1)*7+1]
                    + wv4.z*Wp[(col+2)*7+1] + wv4.w*Wp[(col+3)*7+1];
                s2 += wv4.x*uv4.x + wv4.y*uv4.y + wv4.z*uv4.z + wv4.w*uv4.w;
            }
            #pragma unroll
            for (int off = 32; off >= 1; off >>= 1) {
                s0 += __shfl_down(s0, off, 64);
                s1 += __shfl_down(s1, off, 64);
                s2 += __shfl_down(s2, off, 64);
            }
            if (lane == 0) {
                sA[ri] = s0;
                sT[ri] = s1;
                sC[ri] = s2 + bih[grow];
            }
        }
    }
    __syncthreads();   // sA/sT/sC ready

    // ---- wave0: gate constants (lanes 0-7) + replicated tagged h0 publish --
    float apk_r=0, apk_z=0, apk_n=0, atp_r=0, atp_z=0, atp_n=0,
          cvt_r=0, cvt_z=0, cvt_n=0, br=0, bz=0, bn=0, hprev=0;
    if (wv == 0) {
        float hinit = 0.f;
        if (lane < JPB) {
            int jj = b*JPB + lane;
            apk_r = sA[lane]; apk_z = sA[8+lane]; apk_n = sA[16+lane];
            atp_r = sT[lane]; atp_z = sT[8+lane]; atp_n = sT[16+lane];
            cvt_r = sC[lane]; cvt_z = sC[8+lane]; cvt_n = sC[16+lane];
            br = bhh[jj]; bz = bhh[jj + Hdim]; bn = bhh[jj + 2*Hdim];
            hprev = smiles[jj];
            hinit = hprev;
        }
        // one wave-store covers all 8 replicas: lane -> (rep=lane>>3, lane&7)
        float hv = __shfl(hinit, lane & 7);
        unsigned w0 = (__float_as_uint(hv) & 0xFFFFFF00u);   // tag 0
        __hip_atomic_store(hq + (size_t)(lane >> 3)*Hdim + b*JPB + (lane & 7), w0,
                           __ATOMIC_RELAXED, __HIP_MEMORY_SCOPE_AGENT);
        if (b == 0 && lane == 0) out[0] = pkdata[0];
    }

    // ================== main recurrence loop ==================
    for (int t = 0; t < Ldim - 1; ++t) {
        const int pr_ = t & 1;
        const unsigned* hin = hq + (size_t)(pr_*NREP + rep)*Hdim;
        const unsigned tt = (unsigned)t & 0xFFu;

        // ---- poll: ONE 8B load = detect AND payload (own replica only) ----
        u64 q;
        for (;;) {
            q = __hip_atomic_load((const u64*)(hin + i0),
                                  __ATOMIC_RELAXED, __HIP_MEMORY_SCOPE_AGENT);
            if (((unsigned)q & 0xFFu) == tt &&
                ((unsigned)(q >> 32) & 0xFFu) == tt) break;
        }
        float h0 = __uint_as_float((unsigned)q         & 0xFFFFFF00u);
        float h1 = __uint_as_float((unsigned)(q >> 32) & 0xFFFFFF00u);
        sh_h[i0]     = h0;
        sh_h[i0 + 1] = h1;

        // local pred partial (pred_{t-1} = W_out . h_t + b_out)
        float wpart = wo0*h0 + wo1*h1;
        #pragma unroll
        for (int off = 32; off >= 1; off >>= 1) wpart += __shfl_down(wpart, off, 64);
        if (lane == 0) swp[pr_][wv] = wpart;
        __syncthreads();                         // B1: h staged

        // ---- dots: 3 gate rows x 16 columns per thread, from LDS ----
        float prd = 0.f, pzd = 0.f, pnd = 0.f;
        #pragma unroll
        for (int c = 0; c < 4; ++c) {
            float4 hv4 = *(const float4*)(sh_h + c*512 + k*4);
            prd += w[0][c].x*hv4.x + w[0][c].y*hv4.y + w[0][c].z*hv4.z + w[0][c].w*hv4.w;
            pzd += w[1][c].x*hv4.x + w[1][c].y*hv4.y + w[1][c].z*hv4.z + w[1][c].w*hv4.w;
            pnd += w[2][c].x*hv4.x + w[2][c].y*hv4.y + w[2][c].z*hv4.z + w[2][c].w*hv4.w;
        }
        #pragma unroll
        for (int off = 32; off >= 1; off >>= 1) {
            prd += __shfl_down(prd, off, 64);
            pzd += __shfl_down(pzd, off, 64);
            pnd += __shfl_down(pnd, off, 64);
        }
        if (lane == 0) { sred[wv][0] = prd; sred[wv][1] = pzd; sred[wv][2] = pnd; }
        __syncthreads();                         // B2: sred ready

        // ---- wave 0: pred, pk, gates, replicated publish, THEN out[t] ----
        if (wv == 0) {
            __builtin_amdgcn_s_setprio(1);       // global critical path starts
            float s = (lane < 16) ? swp[pr_][lane] : 0.f;
            s += __shfl_down(s, 8, 64);
            s += __shfl_down(s, 4, 64);
            s += __shfl_down(s, 2, 64);
            s += __shfl_down(s, 1, 64);
            float pred = __shfl(s, 0) + bo;      // pred_{t-1}
            float pk = (t == 0) ? s_pkd[0] : ((s_tf[t] == 1) ? pred : s_pkd[t]);
            float hvnew = 0.f;
            if (lane < JPB) {
                float dotr = sred[2*lane][0] + sred[2*lane+1][0];
                float dotz = sred[2*lane][1] + sred[2*lane+1][1];
                float dotn = sred[2*lane][2] + sred[2*lane+1][2];
                float tp  = s_tp[t];
                float gr  = apk_r*pk + atp_r*tp + cvt_r + dotr + br;
                float gz  = apk_z*pk + atp_z*tp + cvt_z + dotz + bz;
                float gin = apk_n*pk + atp_n*tp + cvt_n;
                float r = fast_sigmoid(gr);
                float z = fast_sigmoid(gz);
                float n = fast_tanh(gin + r*(dotn + bn));
                hvnew = (1.0f - z)*n + z*hprev;
                hprev = hvnew;
            }
            // one wave-store covers all 8 replicas (critical path)
            float hv = __shfl(hvnew, lane & 7);
            unsigned wpk = (__float_as_uint(hv) & 0xFFFFFF00u)
                         | ((unsigned)(t + 1) & 0xFFu);
            __hip_atomic_store(hq + (size_t)(((pr_^1)*NREP) + (lane >> 3))*Hdim
                                   + b*JPB + (lane & 7), wpk,
                               __ATOMIC_RELAXED, __HIP_MEMORY_SCOPE_AGENT);
            __builtin_amdgcn_s_setprio(0);
            if (b == 0 && lane == 0 && t > 0) out[t] = pred;  // off critical path
        }
    }

    // ---- final: only block 0 polls h_255 (replica 0) and writes out[255] ----
    if (b == 0) {
        const unsigned* hin = hq + (size_t)((((Ldim - 1) & 1))*NREP + 0)*Hdim;
        const unsigned tt = (unsigned)(Ldim - 1) & 0xFFu;
        u64 q;
        for (;;) {
            q = __hip_atomic_load((const u64*)(hin + i0),
                                  __ATOMIC_RELAXED, __HIP_MEMORY_SCOPE_AGENT);
            if (((unsigned)q & 0xFFu) == tt &&
                ((unsigned)(q >> 32) & 0xFFu) == tt) break;
        }
        float h0 = __uint_as_float((unsigned)q         & 0xFFFFFF00u);
        float h1 = __uint_as_float((unsigned)(q >> 32) & 0xFFFFFF00u);
        float wpart = wo0*h0 + wo1*h1;
        #pragma unroll
        for (int off = 32; off >= 1; off >>= 1) wpart += __shfl_down(wpart, off, 64);
        if (lane == 0) swp[1][wv] = wpart;
        __syncthreads();
        if (wv == 0) {
            float s = (lane < 16) ? swp[1][lane] : 0.f;
            s += __shfl_down(s, 8, 64);
            s += __shfl_down(s, 4, 64);
            s += __shfl_down(s, 2, 64);
            s += __shfl_down(s, 1, 64);
            if (lane == 0) out[Ldim - 1] = s + bo;
        }
    }
}

extern "C" void kernel_launch(void* const* d_in, const int* in_sizes, int n_in,
                              void* d_out, int out_size, void* d_ws, size_t ws_size,
                              hipStream_t stream)
{
    const float* tps    = (const float*)d_in[0];   // timepoints (256,1)
    const float* pkdata = (const float*)d_in[1];   // pk_data (256,1)
    // d_in[2] = input_len (unused, static 256)
    const int*   pat    = (const int*)  d_in[3];   // emb_patient
    const float* route  = (const float*)d_in[4];   // drug_route (1,)
    const float* dose   = (const float*)d_in[5];   // dose (1,)
    const float* smiles = (const float*)d_in[6];   // (1, 2048)
    const int*   tfm    = (const int*)  d_in[7];   // tf_mask (256,)
    const float* emb    = (const float*)d_in[8];   // emb_table (8,3)
    const float* Wp     = (const float*)d_in[9];   // W_pre (2048,7)
    const float* bpre   = (const float*)d_in[10];  // b_pre (2048,)
    const float* Wih    = (const float*)d_in[11];  // W_ih (6144,2048)
    const float* Whh    = (const float*)d_in[12];  // W_hh (6144,2048)
    const float* bih    = (const float*)d_in[13];  // b_ih (6144,)
    const float* bhh    = (const float*)d_in[14];  // b_hh (6144,)
    const float* Wout   = (const float*)d_in[15];  // W_out (1,2048)
    const float* bout   = (const float*)d_in[16];  // b_out (1,)
    float* out = (float*)d_out;
    float* ws  = (float*)d_ws;

    hipLaunchKernelGGL(gru_all, dim3(NBLK), dim3(TPB), 0, stream,
                       Whh, bhh, Wout, bout, tps, pkdata, tfm, smiles,
                       Wp, bpre, Wih, bih, dose, route, emb, pat, ws, out);
}

// Round 11
// 958.877 us; speedup vs baseline: 3.0235x; 1.0147x over previous
//
#include <hip/hip_runtime.h>
#include <math.h>

#define Hdim 2048
#define Ldim 256
#define NBLK 256
#define TPB  1024
#define JPB  8      // h-elements per block (Hdim / NBLK)
#define NREP 8      // replicas of the published h (consumers shard by b&7)

typedef unsigned long long u64;

// workspace: packed replicated h buffer: [parity][replica][2048] u32 words.
// word = (f32 bits & 0xFFFFFF00) | step_tag8  — tag rides in the mantissa
// low byte (<=3e-5 relative perturbation). Detect = equality with t.
// Race-free (2-phase: wave0 publishes only after B2, which proves all waves
// passed B1 of this step, i.e. everyone is done reading the parity being
// overwritten).
//
// Protocol ledger:
//  - r9 structure (2 barriers, wave0 funnel, ONE wave-store publish): 1010us.
//  - v2'' per-pair publish: 2899us REFUTED — scattered 4B stores -> ~10x
//    write amplification + staggered tag visibility. The single wave-store
//    covering all 8 replicas x 8 words is load-bearing.
//  - r10 = r9 + fast sigmoid/tanh + setprio on wave0 tail: 973us (measured,
//    WRITE 16MB, FETCH 73MB, VALUBusy 17%).
//  - r11 fused-W_out: FAILED (absmax 1.66) — summing sred[0..15][3] counts
//    the full W_out.h 8x (each wave-PAIR covers all 2048 cols; waves 0+1
//    alone are exact single coverage).
//  - r12 (this) = r11 + fix: pred = sred[0][3] + sred[1][3] + bo (two
//    broadcast LDS reads; pred funnel shorter than r10's shuffle chain).
#define WS_HP 0

__device__ __forceinline__ float fast_sigmoid(float x) {
    return __builtin_amdgcn_rcpf(1.0f + __expf(-x));
}
__device__ __forceinline__ float fast_tanh(float x) {
    // 1 - 2/(1+e^{2x}); saturates correctly at +/-inf
    return 1.0f - 2.0f * __builtin_amdgcn_rcpf(1.0f + __expf(2.0f * x));
}

// ---------------- single fused persistent kernel ----------------------------
// 256 blocks x 1024 threads, 1 block/CU. Block b owns h[j], j = b*8..b*8+7.
// Proven protocol: minimum-hop tagged payload, 8x replicated; producer wave0
// emits ONE wave-store covering all replicas; consumer block polls only
// replica b&7 with ONE 8B load = detect+payload.
__global__ __launch_bounds__(TPB, 4) void gru_all(
    const float* __restrict__ Whh,  const float* __restrict__ bhh,
    const float* __restrict__ Wout, const float* __restrict__ bout,
    const float* __restrict__ tps,  const float* __restrict__ pkdata,
    const int*   __restrict__ tf,   const float* __restrict__ smiles,
    const float* __restrict__ Wp,   const float* __restrict__ bpre,
    const float* __restrict__ Wih,  const float* __restrict__ bih,
    const float* __restrict__ dose, const float* __restrict__ route,
    const float* __restrict__ emb,  const int* __restrict__ pat,
    float* __restrict__ ws, float* __restrict__ out)
{
    const int b    = blockIdx.x;
    const int tid  = threadIdx.x;
    const int k    = tid & 127;     // column group within j (dots)
    const int g    = tid >> 7;      // which j this thread's dot serves
    const int wv   = tid >> 6;      // wave id 0..15
    const int lane = tid & 63;
    const int j    = b*JPB + g;
    const int rep  = b & 7;         // this block's poll replica

    __shared__ float su[Hdim];      // u vector (prep only)
    __shared__ float sh_h[Hdim];
    __shared__ float sred[16][4];   // per-wave dot partials: r,z,n,w
    __shared__ float sfin[16];      // final-output reduce buffer (epilogue)
    __shared__ float sA[24], sT[24], sC[24];   // APK/ATP/CVT for own 24 rows
    __shared__ float s_tp[Ldim];
    __shared__ float s_pkd[Ldim];
    __shared__ int   s_tf[Ldim];

    unsigned* hq = (unsigned*)(ws + WS_HP);

    // small per-step scalars
    for (int i = tid; i < Ldim; i += TPB) {
        s_tp[i]  = tps[i];
        s_pkd[i] = pkdata[i];
        s_tf[i]  = tf[i];
    }

    // ---- prep A: u[i] = Wp[i,2:7].consts + b_pre[i] into LDS ----
    {
        float d = dose[0], rt = route[0];
        int p = pat[0];
        float e0 = emb[p*3+0], e1 = emb[p*3+1], e2 = emb[p*3+2];
        for (int i = tid; i < Hdim; i += TPB) {
            const float* wr = Wp + i*7;
            su[i] = d*wr[2] + e0*wr[3] + e1*wr[4] + e2*wr[5] + rt*wr[6] + bpre[i];
        }
    }

    // W_hh rows -> registers (48 VGPRs), coalesced float4 loads
    float4 w[3][4];
    #pragma unroll
    for (int r = 0; r < 3; ++r) {
        const float* base = Whh + (size_t)(j + r*Hdim) * Hdim;
        #pragma unroll
        for (int c = 0; c < 4; ++c)
            w[r][c] = *(const float4*)(base + c*512 + k*4);
    }

    // W_out slice over this thread's dot columns -> registers (16 VGPRs)
    float4 wout[4];
    #pragma unroll
    for (int c = 0; c < 4; ++c)
        wout[c] = *(const float4*)(Wout + c*512 + k*4);

    // per-thread W_out slice over its staged h pair (epilogue only)
    const int i0 = tid * 2;
    const float wo0 = Wout[i0], wo1 = Wout[i0 + 1];
    const float bo = bout[0];

    __syncthreads();   // su ready

    // ---- prep B: fold this block's 24 W_ih rows ----
    #pragma unroll
    for (int pass = 0; pass < 2; ++pass) {
        int ri = wv + pass*16;
        if (ri < 24) {
            int grow = (ri >> 3)*Hdim + b*JPB + (ri & 7);
            const float* wr = Wih + (size_t)grow * Hdim;
            float s0 = 0.f, s1 = 0.f, s2 = 0.f;
            #pragma unroll
            for (int c = 0; c < 8; ++c) {
                int col = c*256 + lane*4;
                float4 wv4 = *(const float4*)(wr + col);
                float4 uv4 = *(const float4*)(su + col);
                s0 += wv4.x*Wp[(col+0)*7+0] + wv4.y*Wp[(col+1)*7+0]
                    + wv4.z*Wp[(col+2)*7+0] + wv4.w*Wp[(col+3)*7+0];
                s1 += wv4.x*Wp[(col+0)*7+1] + wv4.y*Wp[(col+1)*7+1]
                    + wv4.z*Wp[(col+2)*7+1] + wv4.w*Wp[(col+3)*7+1];
                s2 += wv4.x*uv4.x + wv4.y*uv4.y + wv4.z*uv4.z + wv4.w*uv4.w;
            }
            #pragma unroll
            for (int off = 32; off >= 1; off >>= 1) {
                s0 += __shfl_down(s0, off, 64);
                s1 += __shfl_down(s1, off, 64);
                s2 += __shfl_down(s2, off, 64);
            }
            if (lane == 0) {
                sA[ri] = s0;
                sT[ri] = s1;
                sC[ri] = s2 + bih[grow];
            }
        }
    }
    __syncthreads();   // sA/sT/sC ready

    // ---- wave0: gate constants (lanes 0-7) + replicated tagged h0 publish --
    float apk_r=0, apk_z=0, apk_n=0, atp_r=0, atp_z=0, atp_n=0,
          cvt_r=0, cvt_z=0, cvt_n=0, br=0, bz=0, bn=0, hprev=0;
    if (wv == 0) {
        float hinit = 0.f;
        if (lane < JPB) {
            int jj = b*JPB + lane;
            apk_r = sA[lane]; apk_z = sA[8+lane]; apk_n = sA[16+lane];
            atp_r = sT[lane]; atp_z = sT[8+lane]; atp_n = sT[16+lane];
            cvt_r = sC[lane]; cvt_z = sC[8+lane]; cvt_n = sC[16+lane];
            br = bhh[jj]; bz = bhh[jj + Hdim]; bn = bhh[jj + 2*Hdim];
            hprev = smiles[jj];
            hinit = hprev;
        }
        // one wave-store covers all 8 replicas: lane -> (rep=lane>>3, lane&7)
        float hv = __shfl(hinit, lane & 7);
        unsigned w0 = (__float_as_uint(hv) & 0xFFFFFF00u);   // tag 0
        __hip_atomic_store(hq + (size_t)(lane >> 3)*Hdim + b*JPB + (lane & 7), w0,
                           __ATOMIC_RELAXED, __HIP_MEMORY_SCOPE_AGENT);
        if (b == 0 && lane == 0) out[0] = pkdata[0];
    }

    // ================== main recurrence loop ==================
    for (int t = 0; t < Ldim - 1; ++t) {
        const int pr_ = t & 1;
        const unsigned* hin = hq + (size_t)(pr_*NREP + rep)*Hdim;
        const unsigned tt = (unsigned)t & 0xFFu;

        // ---- poll: ONE 8B load = detect AND payload (own replica only) ----
        u64 q;
        for (;;) {
            q = __hip_atomic_load((const u64*)(hin + i0),
                                  __ATOMIC_RELAXED, __HIP_MEMORY_SCOPE_AGENT);
            if (((unsigned)q & 0xFFu) == tt &&
                ((unsigned)(q >> 32) & 0xFFu) == tt) break;
        }
        float h0 = __uint_as_float((unsigned)q         & 0xFFFFFF00u);
        float h1 = __uint_as_float((unsigned)(q >> 32) & 0xFFFFFF00u);
        sh_h[i0]     = h0;
        sh_h[i0 + 1] = h1;
        __syncthreads();                         // B1: h staged (no pre-reduce)

        // ---- dots: 3 gate rows + fused W_out row, 16 cols/thread, from LDS -
        float prd = 0.f, pzd = 0.f, pnd = 0.f, pwd = 0.f;
        #pragma unroll
        for (int c = 0; c < 4; ++c) {
            float4 hv4 = *(const float4*)(sh_h + c*512 + k*4);
            prd += w[0][c].x*hv4.x + w[0][c].y*hv4.y + w[0][c].z*hv4.z + w[0][c].w*hv4.w;
            pzd += w[1][c].x*hv4.x + w[1][c].y*hv4.y + w[1][c].z*hv4.z + w[1][c].w*hv4.w;
            pnd += w[2][c].x*hv4.x + w[2][c].y*hv4.y + w[2][c].z*hv4.z + w[2][c].w*hv4.w;
            pwd += wout[c].x*hv4.x + wout[c].y*hv4.y + wout[c].z*hv4.z + wout[c].w*hv4.w;
        }
        #pragma unroll
        for (int off = 32; off >= 1; off >>= 1) {
            prd += __shfl_down(prd, off, 64);
            pzd += __shfl_down(pzd, off, 64);
            pnd += __shfl_down(pnd, off, 64);
            pwd += __shfl_down(pwd, off, 64);
        }
        if (lane == 0) {
            sred[wv][0] = prd; sred[wv][1] = pzd;
            sred[wv][2] = pnd; sred[wv][3] = pwd;
        }
        __syncthreads();                         // B2: sred ready

        // ---- wave 0: pred, pk, gates, replicated publish, THEN out[t] ----
        if (wv == 0) {
            __builtin_amdgcn_s_setprio(1);       // global critical path starts
            // waves 0+1 cover all 2048 cols exactly once (k=0..127);
            // two broadcast LDS reads, no shuffle funnel.
            float pred = sred[0][3] + sred[1][3] + bo;   // pred_{t-1}
            float pk = (t == 0) ? s_pkd[0] : ((s_tf[t] == 1) ? pred : s_pkd[t]);
            float hvnew = 0.f;
            if (lane < JPB) {
                float dotr = sred[2*lane][0] + sred[2*lane+1][0];
                float dotz = sred[2*lane][1] + sred[2*lane+1][1];
                float dotn = sred[2*lane][2] + sred[2*lane+1][2];
                float tp  = s_tp[t];
                float gr  = apk_r*pk + atp_r*tp + cvt_r + dotr + br;
                float gz  = apk_z*pk + atp_z*tp + cvt_z + dotz + bz;
                float gin = apk_n*pk + atp_n*tp + cvt_n;
                float r = fast_sigmoid(gr);
                float z = fast_sigmoid(gz);
                float n = fast_tanh(gin + r*(dotn + bn));
                hvnew = (1.0f - z)*n + z*hprev;
                hprev = hvnew;
            }
            // one wave-store covers all 8 replicas (critical path)
            float hv = __shfl(hvnew, lane & 7);
            unsigned wpk = (__float_as_uint(hv) & 0xFFFFFF00u)
                         | ((unsigned)(t + 1) & 0xFFu);
            __hip_atomic_store(hq + (size_t)(((pr_^1)*NREP) + (lane >> 3))*Hdim
                                   + b*JPB + (lane & 7), wpk,
                               __ATOMIC_RELAXED, __HIP_MEMORY_SCOPE_AGENT);
            __builtin_amdgcn_s_setprio(0);
            if (b == 0 && lane == 0 && t > 0) out[t] = pred;  // off critical path
        }
    }

    // ---- final: only block 0 polls h_255 (replica 0) and writes out[255] ----
    if (b == 0) {
        const unsigned* hin = hq + (size_t)((((Ldim - 1) & 1))*NREP + 0)*Hdim;
        const unsigned tt = (unsigned)(Ldim - 1) & 0xFFu;
        u64 q;
        for (;;) {
            q = __hip_atomic_load((const u64*)(hin + i0),
                                  __ATOMIC_RELAXED, __HIP_MEMORY_SCOPE_AGENT);
            if (((unsigned)q & 0xFFu) == tt &&
                ((unsigned)(q >> 32) & 0xFFu) == tt) break;
        }
        float h0 = __uint_as_float((unsigned)q         & 0xFFFFFF00u);
        float h1 = __uint_as_float((unsigned)(q >> 32) & 0xFFFFFF00u);
        float wpart = wo0*h0 + wo1*h1;
        #pragma unroll
        for (int off = 32; off >= 1; off >>= 1) wpart += __shfl_down(wpart, off, 64);
        if (lane == 0) sfin[wv] = wpart;
        __syncthreads();
        if (wv == 0) {
            float s = (lane < 16) ? sfin[lane] : 0.f;
            s += __shfl_down(s, 8, 64);
            s += __shfl_down(s, 4, 64);
            s += __shfl_down(s, 2, 64);
            s += __shfl_down(s, 1, 64);
            if (lane == 0) out[Ldim - 1] = s + bo;
        }
    }
}

extern "C" void kernel_launch(void* const* d_in, const int* in_sizes, int n_in,
                              void* d_out, int out_size, void* d_ws, size_t ws_size,
                              hipStream_t stream)
{
    const float* tps    = (const float*)d_in[0];   // timepoints (256,1)
    const float* pkdata = (const float*)d_in[1];   // pk_data (256,1)
    // d_in[2] = input_len (unused, static 256)
    const int*   pat    = (const int*)  d_in[3];   // emb_patient
    const float* route  = (const float*)d_in[4];   // drug_route (1,)
    const float* dose   = (const float*)d_in[5];   // dose (1,)
    const float* smiles = (const float*)d_in[6];   // (1, 2048)
    const int*   tfm    = (const int*)  d_in[7];   // tf_mask (256,)
    const float* emb    = (const float*)d_in[8];   // emb_table (8,3)
    const float* Wp     = (const float*)d_in[9];   // W_pre (2048,7)
    const float* bpre   = (const float*)d_in[10];  // b_pre (2048,)
    const float* Wih    = (const float*)d_in[11];  // W_ih (6144,2048)
    const float* Whh    = (const float*)d_in[12];  // W_hh (6144,2048)
    const float* bih    = (const float*)d_in[13];  // b_ih (6144,)
    const float* bhh    = (const float*)d_in[14];  // b_hh (6144,)
    const float* Wout   = (const float*)d_in[15];  // W_out (1,2048)
    const float* bout   = (const float*)d_in[16];  // b_out (1,)
    float* out = (float*)d_out;
    float* ws  = (float*)d_ws;

    hipLaunchKernelGGL(gru_all, dim3(NBLK), dim3(TPB), 0, stream,
                       Whh, bhh, Wout, bout, tps, pkdata, tfm, smiles,
                       Wp, bpre, Wih, bih, dose, route, emb, pat, ws, out);
}